// Round 1
// baseline (1772.977 us; speedup 1.0000x reference)
//
#include <hip/hip_runtime.h>

#define N0c 100000
#define N1c 20000
#define Ec 320000
#define Tc 8
#define DINc 128
#define Hc 64
#define Cc 16

#define EB_WAVES 8
#define EB_THREADS (EB_WAVES * 64)
#define NB_WAVES 8
#define NB_THREADS (NB_WAVES * 64)

__device__ __forceinline__ float sigmoidf_(float x) {
    return 1.0f / (1.0f + __expf(-x));
}
__device__ __forceinline__ float tanhf_(float x) {
    // 2*sigmoid(2x)-1 ; saturates correctly for large |x|
    return 2.0f / (1.0f + __expf(-2.0f * x)) - 1.0f;
}

// ---------------- Edge kernel: LSTM + rank-1 removal + edge MLP + scatter ----
__global__ __launch_bounds__(EB_THREADS, 1)
void edge_kernel(const float* __restrict__ nf,    // [N0,128]
                 const float* __restrict__ ef,    // [E,8,15]
                 const float* __restrict__ st,    // [E,8]
                 const float* __restrict__ pw,    // [128]
                 const float* __restrict__ Wih,   // [16,256]
                 const float* __restrict__ Whh,   // [64,256]
                 const float* __restrict__ lb,    // [256]
                 const float* __restrict__ eW,    // [192,64]
                 const float* __restrict__ ebias, // [64]
                 const int* __restrict__ elen,
                 const int* __restrict__ src,
                 const int* __restrict__ dst,
                 float* __restrict__ agg,         // [N1,64]
                 int nWavesTotal)
{
    // Wih rearranged: sWih[k*256 + l*4 + g] = Wih[k*256 + g*64 + l]
    __shared__ float sWih[16 * 256];   // 16 KB
    __shared__ float sWhh[64 * 256];   // 64 KB  (same rearrangement)
    __shared__ float sEW[192 * 64];    // 48 KB  (row-major as given)
    __shared__ float sX[EB_WAVES][Tc * 16];  // 4 KB
    __shared__ float sH[EB_WAVES][64];       // 2 KB
    __shared__ float sCat[EB_WAVES][192];    // 6 KB

    const int tid = threadIdx.x;

    for (int idx = tid; idx < 16 * 256; idx += EB_THREADS) {
        int k = idx >> 8, r = idx & 255;
        int g = r >> 6, l = r & 63;
        sWih[k * 256 + l * 4 + g] = Wih[idx];
    }
    for (int idx = tid; idx < 64 * 256; idx += EB_THREADS) {
        int j = idx >> 8, r = idx & 255;
        int g = r >> 6, l = r & 63;
        sWhh[j * 256 + l * 4 + g] = Whh[idx];
    }
    for (int idx = tid; idx < 192 * 64; idx += EB_THREADS) sEW[idx] = eW[idx];
    __syncthreads();

    const int lane = tid & 63;
    const int wv = tid >> 6;
    const int gwave = blockIdx.x * EB_WAVES + wv;

    // per-lane constants (uniform over edges)
    const float b0 = lb[lane], b1 = lb[64 + lane], b2 = lb[128 + lane], b3 = lb[192 + lane];
    const float p0 = pw[lane], p1 = pw[64 + lane];
    const float ebv = ebias[lane];

    for (int e = gwave; e < Ec; e += nWavesTotal) {
        const int len = elen[e];

        // stage x = [edge_features | time] for t < len
        for (int i = lane; i < len * 15; i += 64) {
            int t = i / 15, k = i - t * 15;
            sX[wv][t * 16 + k] = ef[(size_t)e * 120 + i];
        }
        if (lane < len) sX[wv][lane * 16 + 15] = st[e * 8 + lane];

        // LSTM over len steps; lane owns hidden unit `lane`
        float h = 0.f, c = 0.f;
        for (int t = 0; t < len; ++t) {
            sH[wv][lane] = h;
            float a0 = b0, a1 = b1, a2 = b2, a3 = b3;
            #pragma unroll
            for (int k = 0; k < 16; ++k) {
                float xv = sX[wv][t * 16 + k];
                const float4 w = *(const float4*)&sWih[k * 256 + lane * 4];
                a0 += xv * w.x; a1 += xv * w.y; a2 += xv * w.z; a3 += xv * w.w;
            }
            if (t > 0) {  // h == 0 at t=0: skip recurrent matmul
                #pragma unroll 8
                for (int j = 0; j < 64; ++j) {
                    float hv = sH[wv][j];
                    const float4 w = *(const float4*)&sWhh[j * 256 + lane * 4];
                    a0 += hv * w.x; a1 += hv * w.y; a2 += hv * w.z; a3 += hv * w.w;
                }
            }
            float ig = sigmoidf_(a0);
            float fg = sigmoidf_(a1);
            float gg = tanhf_(a2);
            float og = sigmoidf_(a3);
            c = fg * c + ig * gg;
            h = og * tanhf_(c);
        }
        // h is e_enc[lane]

        // h_src gather + rank-1 removal
        const int s = src[e];
        float hs0 = nf[(size_t)s * 128 + lane];
        float hs1 = nf[(size_t)s * 128 + 64 + lane];
        float part = hs0 * p0 + hs1 * p1;
        #pragma unroll
        for (int off = 32; off; off >>= 1) part += __shfl_xor(part, off);
        float hp0 = hs0 - part * p0;
        float hp1 = hs1 - part * p1;

        sCat[wv][lane] = hp0;
        sCat[wv][64 + lane] = hp1;
        sCat[wv][128 + lane] = h;

        // m = relu(cat @ eW + eb)
        float acc = ebv;
        #pragma unroll 8
        for (int cc = 0; cc < 192; ++cc) {
            acc += sCat[wv][cc] * sEW[cc * 64 + lane];
        }
        acc = fmaxf(acc, 0.f);
        atomicAdd(&agg[(size_t)dst[e] * 64 + lane], acc);
    }
}

// ---------------- Node kernel: self path + node MLP + fc ----------------
__global__ __launch_bounds__(NB_THREADS, 1)
void node_kernel(const float* __restrict__ nf,    // [N0,128]
                 const float* __restrict__ sgn,   // [N1]
                 const float* __restrict__ eW,    // [192,64] (rows 0..127 used)
                 const float* __restrict__ ebias, // [64]
                 const float* __restrict__ nW,    // [192,64]
                 const float* __restrict__ nbias, // [64]
                 const float* __restrict__ fcW,   // [64,16]
                 const float* __restrict__ fcb,   // [16]
                 const int* __restrict__ lnid,    // [N1]
                 const float* __restrict__ agg,   // [N1,64]
                 float* __restrict__ out,         // [N1,16]
                 int nWavesTotal)
{
    __shared__ float sEW[128 * 64];   // 32 KB
    __shared__ float sNW[192 * 64];   // 48 KB
    __shared__ float sFC[64 * 16];    // 4 KB
    __shared__ float sCat[NB_WAVES][192];
    __shared__ float sAct[NB_WAVES][64];

    const int tid = threadIdx.x;
    for (int idx = tid; idx < 128 * 64; idx += NB_THREADS) sEW[idx] = eW[idx];
    for (int idx = tid; idx < 192 * 64; idx += NB_THREADS) sNW[idx] = nW[idx];
    for (int idx = tid; idx < 64 * 16; idx += NB_THREADS) sFC[idx] = fcW[idx];
    __syncthreads();

    const int lane = tid & 63;
    const int wv = tid >> 6;
    const int gwave = blockIdx.x * NB_WAVES + wv;

    const float ebv = ebias[lane];
    const float nbv = nbias[lane];
    const float fcbv = (lane < 16) ? fcb[lane] : 0.f;

    for (int n = gwave; n < N1c; n += nWavesTotal) {
        const int nid = lnid[n];
        float sh0 = nf[(size_t)nid * 128 + lane];
        float sh1 = nf[(size_t)nid * 128 + 64 + lane];
        sCat[wv][lane] = sh0;
        sCat[wv][64 + lane] = sh1;

        // self_h_tmp = self_h @ eW[:128] + eb
        float tmp = ebv;
        #pragma unroll 8
        for (int cc = 0; cc < 128; ++cc) {
            tmp += sCat[wv][cc] * sEW[cc * 64 + lane];
        }
        float hu = (agg[(size_t)n * 64 + lane] - tmp) * sgn[n];
        sCat[wv][128 + lane] = hu;

        float acc = nbv;
        #pragma unroll 8
        for (int cc = 0; cc < 192; ++cc) {
            acc += sCat[wv][cc] * sNW[cc * 64 + lane];
        }
        acc = fmaxf(acc, 0.f);
        sAct[wv][lane] = acc;

        if (lane < 16) {
            float o = fcbv;
            #pragma unroll
            for (int j = 0; j < 64; ++j) {
                o += sAct[wv][j] * sFC[j * 16 + lane];
            }
            out[(size_t)n * 16 + lane] = o;
        }
    }
}

extern "C" void kernel_launch(void* const* d_in, const int* in_sizes, int n_in,
                              void* d_out, int out_size, void* d_ws, size_t ws_size,
                              hipStream_t stream) {
    const float* nf  = (const float*)d_in[0];
    const float* ef  = (const float*)d_in[1];
    const float* st  = (const float*)d_in[2];
    const float* sgn = (const float*)d_in[3];
    const float* pw  = (const float*)d_in[4];
    const float* Wih = (const float*)d_in[5];
    const float* Whh = (const float*)d_in[6];
    const float* lb  = (const float*)d_in[7];
    const float* eW  = (const float*)d_in[8];
    const float* eb  = (const float*)d_in[9];
    const float* nW  = (const float*)d_in[10];
    const float* nb  = (const float*)d_in[11];
    const float* fcW = (const float*)d_in[12];
    const float* fcb = (const float*)d_in[13];
    const int* elen = (const int*)d_in[14];
    const int* src  = (const int*)d_in[15];
    const int* dst  = (const int*)d_in[16];
    const int* lnid = (const int*)d_in[17];

    float* out = (float*)d_out;
    float* agg = (float*)d_ws;  // [N1,64] fp32 = 5.12 MB

    hipMemsetAsync(agg, 0, (size_t)N1c * 64 * sizeof(float), stream);

    const int egrid = 1024;
    edge_kernel<<<egrid, EB_THREADS, 0, stream>>>(
        nf, ef, st, pw, Wih, Whh, lb, eW, eb, elen, src, dst, agg,
        egrid * EB_WAVES);

    const int ngrid = 512;
    node_kernel<<<ngrid, NB_THREADS, 0, stream>>>(
        nf, sgn, eW, eb, nW, nb, fcW, fcb, lnid, agg, out,
        ngrid * NB_WAVES);
}